// Round 1
// baseline (2212.478 us; speedup 1.0000x reference)
//
#include <hip/hip_runtime.h>

// ICNN forward-of-gradient: out = 0.5*d(scalar)/dx + 0.5*x
// B=8192, D=128, H=512, L=10, fp32 throughout (no fp32 MFMA on CDNA4 -> VALU).

#define Bn 8192
#define Dn 128
#define Hn 512
#define Ln 10

constexpr float NS = 0.2f;   // leaky-relu negative slope

#define BM 64
#define BN 64
#define BK 16
#define LDS_STRIDE (BM + 4)   // 68 floats: float4-aligned rows, conflict-light

// ---------------- shared helpers ----------------

// NT phase: C[m,n] += sum_k A[row0+m, k] * Bop[col0+n, k]   (both row-major, reduce contiguous)
template <int K>
__device__ __forceinline__ void phase_nt(const float* __restrict__ A, int lda,
                                         const float* __restrict__ Bop, int ldb,
                                         int row0, int col0, int tid,
                                         float (&acc)[4][4],
                                         float (*As)[LDS_STRIDE], float (*Bs)[LDS_STRIDE]) {
    const int tx = tid & 15, ty = tid >> 4;
    const int lr = tid >> 2;           // 0..63
    const int lk = (tid & 3) << 2;     // 0,4,8,12
    for (int k0 = 0; k0 < K; k0 += BK) {
        float4 av = *(const float4*)(A   + (size_t)(row0 + lr) * lda + k0 + lk);
        float4 bv = *(const float4*)(Bop + (size_t)(col0 + lr) * ldb + k0 + lk);
        __syncthreads();
        As[lk + 0][lr] = av.x; As[lk + 1][lr] = av.y; As[lk + 2][lr] = av.z; As[lk + 3][lr] = av.w;
        Bs[lk + 0][lr] = bv.x; Bs[lk + 1][lr] = bv.y; Bs[lk + 2][lr] = bv.z; Bs[lk + 3][lr] = bv.w;
        __syncthreads();
#pragma unroll
        for (int k = 0; k < BK; ++k) {
            float4 a4 = *(const float4*)&As[k][ty << 2];
            float4 b4 = *(const float4*)&Bs[k][tx << 2];
            float af[4] = {a4.x, a4.y, a4.z, a4.w};
            float bf[4] = {b4.x, b4.y, b4.z, b4.w};
#pragma unroll
            for (int i = 0; i < 4; ++i)
#pragma unroll
                for (int j = 0; j < 4; ++j) acc[i][j] += af[i] * bf[j];
        }
    }
}

// NN phase: C[m,n] += sum_k A[row0+m, k] * Bop[k, col0+n]
template <int K>
__device__ __forceinline__ void phase_nn(const float* __restrict__ A, int lda,
                                         const float* __restrict__ Bop, int ldb,
                                         int row0, int col0, int tid,
                                         float (&acc)[4][4],
                                         float (*As)[LDS_STRIDE], float (*Bs)[LDS_STRIDE]) {
    const int tx = tid & 15, ty = tid >> 4;
    const int lr = tid >> 2;
    const int lk = (tid & 3) << 2;
    const int kr = tid >> 4;           // 0..15
    const int nc = (tid & 15) << 2;    // 0..60
    for (int k0 = 0; k0 < K; k0 += BK) {
        float4 av = *(const float4*)(A   + (size_t)(row0 + lr) * lda + k0 + lk);
        float4 bv = *(const float4*)(Bop + (size_t)(k0 + kr) * ldb + col0 + nc);
        __syncthreads();
        As[lk + 0][lr] = av.x; As[lk + 1][lr] = av.y; As[lk + 2][lr] = av.z; As[lk + 3][lr] = av.w;
        *(float4*)&Bs[kr][nc] = bv;
        __syncthreads();
#pragma unroll
        for (int k = 0; k < BK; ++k) {
            float4 a4 = *(const float4*)&As[k][ty << 2];
            float4 b4 = *(const float4*)&Bs[k][tx << 2];
            float af[4] = {a4.x, a4.y, a4.z, a4.w};
            float bf[4] = {b4.x, b4.y, b4.z, b4.w};
#pragma unroll
            for (int i = 0; i < 4; ++i)
#pragma unroll
                for (int j = 0; j < 4; ++j) acc[i][j] += af[i] * bf[j];
        }
    }
}

// ---------------- kernels ----------------

// Forward layer: z = lrelu( [zprev @ Wz(l-1)^T] + (x@Wq_l^T)^2 + x@Wl_l^T + bl_l ), store mask
__global__ __launch_bounds__(256) void fwd_layer_kernel(
    const float* __restrict__ x, const float* __restrict__ zprev,
    const float* __restrict__ Wz,     // layer slice [H,H] or nullptr for l=0
    const float* __restrict__ Wq, const float* __restrict__ Wl,
    const float* __restrict__ bl,     // layer slice [H]
    float* __restrict__ zout, unsigned char* __restrict__ mask) {
    __shared__ float As[BK][LDS_STRIDE];
    __shared__ float Bs[BK][LDS_STRIDE];
    const int tid = threadIdx.x;
    const int tx = tid & 15, ty = tid >> 4;
    const int row0 = blockIdx.x * BM, col0 = blockIdx.y * BN;

    float accz[4][4] = {{0.f}};
    float accu[4][4] = {{0.f}};
    float accv[4][4] = {{0.f}};

    if (Wz) phase_nt<Hn>(zprev, Hn, Wz, Hn, row0, col0, tid, accz, As, Bs);
    phase_nt<Dn>(x, Dn, Wq, Dn, row0, col0, tid, accu, As, Bs);
    phase_nt<Dn>(x, Dn, Wl, Dn, row0, col0, tid, accv, As, Bs);

#pragma unroll
    for (int i = 0; i < 4; ++i) {
        const int r = row0 + (ty << 2) + i;
        const int c = col0 + (tx << 2);
        float4 zt; uchar4 mt;
        {
            float pre = accz[i][0] + accu[i][0] * accu[i][0] + accv[i][0] + bl[c + 0];
            mt.x = pre >= 0.f; zt.x = pre >= 0.f ? pre : NS * pre;
        }
        {
            float pre = accz[i][1] + accu[i][1] * accu[i][1] + accv[i][1] + bl[c + 1];
            mt.y = pre >= 0.f; zt.y = pre >= 0.f ? pre : NS * pre;
        }
        {
            float pre = accz[i][2] + accu[i][2] * accu[i][2] + accv[i][2] + bl[c + 2];
            mt.z = pre >= 0.f; zt.z = pre >= 0.f ? pre : NS * pre;
        }
        {
            float pre = accz[i][3] + accu[i][3] * accu[i][3] + accv[i][3] + bl[c + 3];
            mt.w = pre >= 0.f; zt.w = pre >= 0.f ? pre : NS * pre;
        }
        *(float4*)(zout + (size_t)r * Hn + c) = zt;
        *(uchar4*)(mask + (size_t)r * Hn + c) = mt;
    }
}

// u_l = x @ Wq_l^T  (plain NT gemm K=128)
__global__ __launch_bounds__(256) void gemm_u_kernel(
    const float* __restrict__ x, const float* __restrict__ Wq, float* __restrict__ u) {
    __shared__ float As[BK][LDS_STRIDE];
    __shared__ float Bs[BK][LDS_STRIDE];
    const int tid = threadIdx.x;
    const int tx = tid & 15, ty = tid >> 4;
    const int row0 = blockIdx.x * BM, col0 = blockIdx.y * BN;
    float acc[4][4] = {{0.f}};
    phase_nt<Dn>(x, Dn, Wq, Dn, row0, col0, tid, acc, As, Bs);
#pragma unroll
    for (int i = 0; i < 4; ++i) {
        const int r = row0 + (ty << 2) + i;
        const int c = col0 + (tx << 2);
        float4 o = {acc[i][0], acc[i][1], acc[i][2], acc[i][3]};
        *(float4*)(u + (size_t)r * Hn + c) = o;
    }
}

// ga_{l-1} = (ga_l @ Wz(l-1)) * lrelu'(mask_{l-1})   (NN gemm K=512)
__global__ __launch_bounds__(256) void bwd_g_kernel(
    const float* __restrict__ ga, const float* __restrict__ Wz,
    const unsigned char* __restrict__ maskprev, float* __restrict__ gaout) {
    __shared__ float As[BK][LDS_STRIDE];
    __shared__ float Bs[BK][LDS_STRIDE];
    const int tid = threadIdx.x;
    const int tx = tid & 15, ty = tid >> 4;
    const int row0 = blockIdx.x * BM, col0 = blockIdx.y * BN;
    float acc[4][4] = {{0.f}};
    phase_nn<Hn>(ga, Hn, Wz, Hn, row0, col0, tid, acc, As, Bs);
#pragma unroll
    for (int i = 0; i < 4; ++i) {
        const int r = row0 + (ty << 2) + i;
        const int c = col0 + (tx << 2);
        uchar4 m = *(const uchar4*)(maskprev + (size_t)r * Hn + c);
        float4 o;
        o.x = acc[i][0] * (m.x ? 1.f : NS);
        o.y = acc[i][1] * (m.y ? 1.f : NS);
        o.z = acc[i][2] * (m.z ? 1.f : NS);
        o.w = acc[i][3] * (m.w ? 1.f : NS);
        *(float4*)(gaout + (size_t)r * Hn + c) = o;
    }
}

// gx[b,d] (+)= sum_h ga[b,h]*(2*u[b,h]*Wq[h,d] + Wl[h,d])   (dual NN gemm K=512, N=128)
__global__ __launch_bounds__(256) void bwd_x_kernel(
    const float* __restrict__ ga, const float* __restrict__ u,
    const float* __restrict__ Wq, const float* __restrict__ Wl,
    float* __restrict__ gx, int addTo) {
    __shared__ float As1[BK][LDS_STRIDE];
    __shared__ float As2[BK][LDS_STRIDE];
    __shared__ float Bq[BK][LDS_STRIDE];
    __shared__ float Bl[BK][LDS_STRIDE];
    const int tid = threadIdx.x;
    const int tx = tid & 15, ty = tid >> 4;
    const int row0 = blockIdx.x * BM, col0 = blockIdx.y * BN;
    const int lr = tid >> 2;
    const int lk = (tid & 3) << 2;
    const int kr = tid >> 4;
    const int nc = (tid & 15) << 2;
    float acc[4][4] = {{0.f}};
    for (int k0 = 0; k0 < Hn; k0 += BK) {
        float4 gv = *(const float4*)(ga + (size_t)(row0 + lr) * Hn + k0 + lk);
        float4 uv = *(const float4*)(u  + (size_t)(row0 + lr) * Hn + k0 + lk);
        float4 qv = *(const float4*)(Wq + (size_t)(k0 + kr) * Dn + col0 + nc);
        float4 lv = *(const float4*)(Wl + (size_t)(k0 + kr) * Dn + col0 + nc);
        __syncthreads();
        As1[lk + 0][lr] = gv.x * 2.f * uv.x;
        As1[lk + 1][lr] = gv.y * 2.f * uv.y;
        As1[lk + 2][lr] = gv.z * 2.f * uv.z;
        As1[lk + 3][lr] = gv.w * 2.f * uv.w;
        As2[lk + 0][lr] = gv.x; As2[lk + 1][lr] = gv.y; As2[lk + 2][lr] = gv.z; As2[lk + 3][lr] = gv.w;
        *(float4*)&Bq[kr][nc] = qv;
        *(float4*)&Bl[kr][nc] = lv;
        __syncthreads();
#pragma unroll
        for (int k = 0; k < BK; ++k) {
            float4 a14 = *(const float4*)&As1[k][ty << 2];
            float4 a24 = *(const float4*)&As2[k][ty << 2];
            float4 bq4 = *(const float4*)&Bq[k][tx << 2];
            float4 bl4 = *(const float4*)&Bl[k][tx << 2];
            float a1[4] = {a14.x, a14.y, a14.z, a14.w};
            float a2[4] = {a24.x, a24.y, a24.z, a24.w};
            float bq[4] = {bq4.x, bq4.y, bq4.z, bq4.w};
            float bl_[4] = {bl4.x, bl4.y, bl4.z, bl4.w};
#pragma unroll
            for (int i = 0; i < 4; ++i)
#pragma unroll
                for (int j = 0; j < 4; ++j) acc[i][j] += a1[i] * bq[j] + a2[i] * bl_[j];
        }
    }
#pragma unroll
    for (int i = 0; i < 4; ++i) {
        const int r = row0 + (ty << 2) + i;
        const int c = col0 + (tx << 2);
        float4 o = {acc[i][0], acc[i][1], acc[i][2], acc[i][3]};
        if (addTo) {
            float4 g = *(const float4*)(gx + (size_t)r * Dn + c);
            o.x += g.x; o.y += g.y; o.z += g.z; o.w += g.w;
        }
        *(float4*)(gx + (size_t)r * Dn + c) = o;
    }
}

// ga_9 = wz_out[h] * lrelu'(mask_9)
__global__ __launch_bounds__(256) void ga_init_kernel(
    const float* __restrict__ wz_out, const unsigned char* __restrict__ mask9,
    float* __restrict__ ga) {
    const int i = blockIdx.x * 256 + threadIdx.x;
    const int base = i << 2;
    const int h = base & (Hn - 1);
    uchar4 m = *(const uchar4*)(mask9 + base);
    float4 w = *(const float4*)(wz_out + h);
    float4 o;
    o.x = w.x * (m.x ? 1.f : NS);
    o.y = w.y * (m.y ? 1.f : NS);
    o.z = w.z * (m.z ? 1.f : NS);
    o.w = w.w * (m.w ? 1.f : NS);
    *(float4*)(ga + base) = o;
}

// s[b] = dot(x[b,:], wq_out)
__global__ __launch_bounds__(256) void rowdot_kernel(
    const float* __restrict__ x, const float* __restrict__ wq_out, float* __restrict__ s) {
    const int b = blockIdx.x * 4 + (threadIdx.x >> 6);
    const int lane = threadIdx.x & 63;
    float v = x[(size_t)b * Dn + lane] * wq_out[lane] +
              x[(size_t)b * Dn + 64 + lane] * wq_out[64 + lane];
#pragma unroll
    for (int off = 32; off > 0; off >>= 1) v += __shfl_down(v, off, 64);
    if (lane == 0) s[b] = v;
}

// out = 0.5*gx + s[b]*wq_out + 0.5*wl_out + 0.5*x   (gx already in out)
__global__ __launch_bounds__(256) void final_kernel(
    float* __restrict__ out, const float* __restrict__ x, const float* __restrict__ s,
    const float* __restrict__ wq_out, const float* __restrict__ wl_out) {
    const int i = blockIdx.x * 256 + threadIdx.x;
    const int base = i << 2;
    const int b = base >> 7;
    const int d = base & (Dn - 1);
    float4 g = *(const float4*)(out + base);
    float4 xv = *(const float4*)(x + base);
    float4 wq = *(const float4*)(wq_out + d);
    float4 wl = *(const float4*)(wl_out + d);
    const float sb = s[b];
    float4 o;
    o.x = 0.5f * g.x + sb * wq.x + 0.5f * wl.x + 0.5f * xv.x;
    o.y = 0.5f * g.y + sb * wq.y + 0.5f * wl.y + 0.5f * xv.y;
    o.z = 0.5f * g.z + sb * wq.z + 0.5f * wl.z + 0.5f * xv.z;
    o.w = 0.5f * g.w + sb * wq.w + 0.5f * wl.w + 0.5f * xv.w;
    *(float4*)(out + base) = o;
}

extern "C" void kernel_launch(void* const* d_in, const int* in_sizes, int n_in,
                              void* d_out, int out_size, void* d_ws, size_t ws_size,
                              hipStream_t stream) {
    (void)in_sizes; (void)n_in; (void)out_size; (void)ws_size;
    const float* x      = (const float*)d_in[0];
    const float* Wq     = (const float*)d_in[1];
    const float* Wl     = (const float*)d_in[2];
    const float* bl     = (const float*)d_in[3];
    const float* Wz     = (const float*)d_in[4];
    const float* wz_out = (const float*)d_in[5];
    const float* wq_out = (const float*)d_in[6];
    const float* wl_out = (const float*)d_in[7];
    float* out = (float*)d_out;

    // ws layout: zA | zB | P(u) | s | masks   -> needs ~92.3 MB
    float* zA = (float*)d_ws;
    float* zB = zA + (size_t)Bn * Hn;
    float* P  = zB + (size_t)Bn * Hn;
    float* s  = P  + (size_t)Bn * Hn;
    unsigned char* masks = (unsigned char*)(s + Bn);

    const dim3 gBH(Bn / BM, Hn / BN);   // 128 x 8
    const dim3 gBD(Bn / BM, Dn / BN);   // 128 x 2

    rowdot_kernel<<<Bn / 4, 256, 0, stream>>>(x, wq_out, s);

    // forward: z_l in (l even ? zA : zB)
    fwd_layer_kernel<<<gBH, 256, 0, stream>>>(x, nullptr, nullptr, Wq, Wl, bl, zA, masks);
    for (int l = 1; l < Ln; ++l) {
        const float* zin = (l & 1) ? zA : zB;
        float* zo = (l & 1) ? zB : zA;
        fwd_layer_kernel<<<gBH, 256, 0, stream>>>(
            x, zin, Wz + (size_t)(l - 1) * Hn * Hn,
            Wq + (size_t)l * Hn * Dn, Wl + (size_t)l * Hn * Dn, bl + (size_t)l * Hn,
            zo, masks + (size_t)l * Bn * Hn);
    }

    // backward: ga_9 -> zA (z8 dead), ping-pong downwards
    ga_init_kernel<<<(Bn * Hn / 4) / 256, 256, 0, stream>>>(
        wz_out, masks + (size_t)9 * Bn * Hn, zA);
    for (int l = Ln - 1; l >= 0; --l) {
        float* ga = (((Ln - 1 - l) & 1) == 0) ? zA : zB;
        gemm_u_kernel<<<gBH, 256, 0, stream>>>(x, Wq + (size_t)l * Hn * Dn, P);
        bwd_x_kernel<<<gBD, 256, 0, stream>>>(
            ga, P, Wq + (size_t)l * Hn * Dn, Wl + (size_t)l * Hn * Dn, out,
            (l == Ln - 1) ? 0 : 1);
        if (l > 0) {
            float* gaout = (((Ln - 1 - l) & 1) == 0) ? zB : zA;
            bwd_g_kernel<<<gBH, 256, 0, stream>>>(
                ga, Wz + (size_t)(l - 1) * Hn * Hn, masks + (size_t)(l - 1) * Bn * Hn, gaout);
        }
    }

    final_kernel<<<(Bn * Dn / 4) / 256, 256, 0, stream>>>(out, x, s, wq_out, wl_out);
}

// Round 2
// 930.903 us; speedup vs baseline: 2.3767x; 2.3767x over previous
//
#include <hip/hip_runtime.h>

// ICNN forward-of-gradient: out = 0.5*d(scalar)/dx + 0.5*x
// R2: all GEMMs on bf16 MFMA (16x16x32) with hi/lo split (3-product ~ fp32 accuracy).

#define Bn 8192
#define Dn 128
#define Hn 512
#define Ln 10

constexpr float NS = 0.2f;

typedef __attribute__((ext_vector_type(8))) short short8;   // 8 bf16 = 4 VGPRs (A/B frag)
typedef __attribute__((ext_vector_type(4))) float f32x4;    // C/D frag

typedef const __attribute__((address_space(1))) void GV;
typedef __attribute__((address_space(3))) void LV;

__device__ __forceinline__ void gload16(const void* g, void* l) {
    __builtin_amdgcn_global_load_lds((GV*)g, (LV*)l, 16, 0, 0);
}

#define MFMA(acc, a, b) acc = __builtin_amdgcn_mfma_f32_16x16x32_bf16(a, b, acc, 0, 0, 0)

__device__ __forceinline__ unsigned short bf16_rne(float v) {
    unsigned u = __float_as_uint(v);
    u += 0x7FFFu + ((u >> 16) & 1u);
    return (unsigned short)(u >> 16);
}
__device__ __forceinline__ float bf2f(unsigned short h) {
    return __uint_as_float(((unsigned)h) << 16);
}
__device__ __forceinline__ void split2(float v, unsigned short& h, unsigned short& l) {
    h = bf16_rne(v);
    l = bf16_rne(v - bf2f(h));
}

// ---------------- prep kernels ----------------

__global__ __launch_bounds__(256) void split_flat(const float* __restrict__ in,
        unsigned short* __restrict__ hi, unsigned short* __restrict__ lo, int n4) {
    int i = blockIdx.x * 256 + threadIdx.x;
    if (i >= n4) return;
    float4 v = ((const float4*)in)[i];
    ushort4 h, l;
    split2(v.x, h.x, l.x);
    split2(v.y, h.y, l.y);
    split2(v.z, h.z, l.z);
    split2(v.w, h.w, l.w);
    ((ushort4*)hi)[i] = h;
    ((ushort4*)lo)[i] = l;
}

// per-layer transpose+split: in [R,C] fp32 -> out [C,R] bf16 hi/lo (layer = blockIdx.z)
__global__ __launch_bounds__(256) void transpose_split(const float* __restrict__ in,
        unsigned short* __restrict__ hi, unsigned short* __restrict__ lo, int R, int C) {
    __shared__ float t[32][33];
    const size_t off = (size_t)blockIdx.z * R * C;
    const float* src = in + off;
    unsigned short* dh = hi + off;
    unsigned short* dl = lo + off;
    const int r0 = blockIdx.x * 32, c0 = blockIdx.y * 32;
    const int tr = threadIdx.x >> 5, tc = threadIdx.x & 31;
#pragma unroll
    for (int i = 0; i < 4; ++i)
        t[tr + 8 * i][tc] = src[(size_t)(r0 + tr + 8 * i) * C + c0 + tc];
    __syncthreads();
#pragma unroll
    for (int i = 0; i < 4; ++i) {
        float v = t[tc][tr + 8 * i];
        unsigned short h, l; split2(v, h, l);
        size_t o = (size_t)(c0 + tr + 8 * i) * R + r0 + tc;
        dh[o] = h; dl[o] = l;
    }
}

// ---------------- fwd layer: 128x64 tile, NT, 3-product split ----------------
// pre = zprev@Wz^T + (x@Wq^T)^2 + x@Wl^T + bl ; z=lrelu(pre) -> zhi/zlo, mask bits

__global__ __launch_bounds__(256) void fwd_mfma(
    const unsigned short* __restrict__ xh, const unsigned short* __restrict__ xl,
    const unsigned short* __restrict__ zph, const unsigned short* __restrict__ zpl,
    const unsigned short* __restrict__ Wzh, const unsigned short* __restrict__ Wzl,
    const unsigned short* __restrict__ Wqh, const unsigned short* __restrict__ Wql,
    const unsigned short* __restrict__ Wlh, const unsigned short* __restrict__ Wll,
    const float* __restrict__ bl,
    unsigned short* __restrict__ zoh, unsigned short* __restrict__ zol,
    unsigned short* __restrict__ mask16, int hasZ)
{
    __shared__ __align__(16) char smem[32768];
    unsigned short* Ah  = (unsigned short*)smem;            // [128][32]
    unsigned short* Al  = (unsigned short*)(smem + 8192);
    unsigned short* B0h = (unsigned short*)(smem + 16384);  // [64][32]
    unsigned short* B0l = (unsigned short*)(smem + 20480);
    unsigned short* B1h = (unsigned short*)(smem + 24576);
    unsigned short* B1l = (unsigned short*)(smem + 28672);

    const int tid = threadIdx.x;
    const int w = tid >> 6, lane = tid & 63;
    const int lq = lane >> 4, lc = lane & 15;
    const int wm = (w & 1) * 64, wn = (w >> 1) * 32;
    const int row0 = blockIdx.x * 128, col0 = blockIdx.y * 64;
    const int sr = lane >> 2, sk = (lane & 3) * 8;

    f32x4 accz[4][2], accu[4][2], accv[4][2];
#pragma unroll
    for (int i = 0; i < 4; ++i)
#pragma unroll
        for (int j = 0; j < 2; ++j)
#pragma unroll
            for (int r = 0; r < 4; ++r) { accz[i][j][r] = 0.f; accu[i][j][r] = 0.f; accv[i][j][r] = 0.f; }

    if (hasZ) {
        for (int k0 = 0; k0 < Hn; k0 += 32) {
            __syncthreads();
            for (int c = w; c < 8; c += 4) {
                size_t go = (size_t)(row0 + c * 16 + sr) * Hn + k0 + sk;
                gload16(zph + go, Ah + c * 512);
                gload16(zpl + go, Al + c * 512);
            }
            {
                int c = w;
                size_t go = (size_t)(col0 + c * 16 + sr) * Hn + k0 + sk;
                gload16(Wzh + go, B0h + c * 512);
                gload16(Wzl + go, B0l + c * 512);
            }
            __syncthreads();
            short8 ah[4], al[4];
#pragma unroll
            for (int mt = 0; mt < 4; ++mt) {
                int ao = (wm + mt * 16 + lc) * 32 + lq * 8;
                ah[mt] = *(const short8*)(Ah + ao);
                al[mt] = *(const short8*)(Al + ao);
            }
#pragma unroll
            for (int nt = 0; nt < 2; ++nt) {
                int bo = (wn + nt * 16 + lc) * 32 + lq * 8;
                short8 bh = *(const short8*)(B0h + bo);
                short8 bv = *(const short8*)(B0l + bo);
#pragma unroll
                for (int mt = 0; mt < 4; ++mt) {
                    MFMA(accz[mt][nt], ah[mt], bh);
                    MFMA(accz[mt][nt], ah[mt], bv);
                    MFMA(accz[mt][nt], al[mt], bh);
                }
            }
        }
    }

    for (int k0 = 0; k0 < Dn; k0 += 32) {
        __syncthreads();
        for (int c = w; c < 8; c += 4) {
            size_t go = (size_t)(row0 + c * 16 + sr) * Dn + k0 + sk;
            gload16(xh + go, Ah + c * 512);
            gload16(xl + go, Al + c * 512);
        }
        {
            int c = w;
            size_t go = (size_t)(col0 + c * 16 + sr) * Dn + k0 + sk;
            gload16(Wqh + go, B0h + c * 512);
            gload16(Wql + go, B0l + c * 512);
            gload16(Wlh + go, B1h + c * 512);
            gload16(Wll + go, B1l + c * 512);
        }
        __syncthreads();
        short8 ah[4], al[4];
#pragma unroll
        for (int mt = 0; mt < 4; ++mt) {
            int ao = (wm + mt * 16 + lc) * 32 + lq * 8;
            ah[mt] = *(const short8*)(Ah + ao);
            al[mt] = *(const short8*)(Al + ao);
        }
#pragma unroll
        for (int nt = 0; nt < 2; ++nt) {
            int bo = (wn + nt * 16 + lc) * 32 + lq * 8;
            short8 bqh = *(const short8*)(B0h + bo);
            short8 bql = *(const short8*)(B0l + bo);
            short8 blh = *(const short8*)(B1h + bo);
            short8 bll = *(const short8*)(B1l + bo);
#pragma unroll
            for (int mt = 0; mt < 4; ++mt) {
                MFMA(accu[mt][nt], ah[mt], bqh);
                MFMA(accu[mt][nt], ah[mt], bql);
                MFMA(accu[mt][nt], al[mt], bqh);
                MFMA(accv[mt][nt], ah[mt], blh);
                MFMA(accv[mt][nt], ah[mt], bll);
                MFMA(accv[mt][nt], al[mt], blh);
            }
        }
    }

#pragma unroll
    for (int nt = 0; nt < 2; ++nt) {
        const int colb = col0 + wn + nt * 16;
        const int col = colb + lc;
        const float blv = bl[col];
#pragma unroll
        for (int mt = 0; mt < 4; ++mt) {
            const int rowb = row0 + wm + mt * 16;
#pragma unroll
            for (int r = 0; r < 4; ++r) {
                float uq = accu[mt][nt][r];
                float pre = accz[mt][nt][r] + uq * uq + accv[mt][nt][r] + blv;
                bool m = pre >= 0.f;
                unsigned long long bal = __ballot(m);
                if (lc == 0) {
                    int rw = rowb + lq * 4 + r;
                    mask16[(size_t)rw * 32 + (colb >> 4)] =
                        (unsigned short)((bal >> (lq * 16)) & 0xFFFFull);
                }
                float zv = m ? pre : NS * pre;
                unsigned short h, l; split2(zv, h, l);
                size_t o = (size_t)(rowb + lq * 4 + r) * Hn + col;
                zoh[o] = h; zol[o] = l;
            }
        }
    }
}

// ---------------- u = x @ Wq_l^T (fp32 out) ----------------

__global__ __launch_bounds__(256) void gemm_u_mfma(
    const unsigned short* __restrict__ xh, const unsigned short* __restrict__ xl,
    const unsigned short* __restrict__ Wqh, const unsigned short* __restrict__ Wql,
    float* __restrict__ u)
{
    __shared__ __align__(16) char smem[24576];
    unsigned short* Ah  = (unsigned short*)smem;
    unsigned short* Al  = (unsigned short*)(smem + 8192);
    unsigned short* B0h = (unsigned short*)(smem + 16384);
    unsigned short* B0l = (unsigned short*)(smem + 20480);

    const int tid = threadIdx.x;
    const int w = tid >> 6, lane = tid & 63;
    const int lq = lane >> 4, lc = lane & 15;
    const int wm = (w & 1) * 64, wn = (w >> 1) * 32;
    const int row0 = blockIdx.x * 128, col0 = blockIdx.y * 64;
    const int sr = lane >> 2, sk = (lane & 3) * 8;

    f32x4 acc[4][2];
#pragma unroll
    for (int i = 0; i < 4; ++i)
#pragma unroll
        for (int j = 0; j < 2; ++j)
#pragma unroll
            for (int r = 0; r < 4; ++r) acc[i][j][r] = 0.f;

    for (int k0 = 0; k0 < Dn; k0 += 32) {
        __syncthreads();
        for (int c = w; c < 8; c += 4) {
            size_t go = (size_t)(row0 + c * 16 + sr) * Dn + k0 + sk;
            gload16(xh + go, Ah + c * 512);
            gload16(xl + go, Al + c * 512);
        }
        {
            int c = w;
            size_t go = (size_t)(col0 + c * 16 + sr) * Dn + k0 + sk;
            gload16(Wqh + go, B0h + c * 512);
            gload16(Wql + go, B0l + c * 512);
        }
        __syncthreads();
        short8 ah[4], al[4];
#pragma unroll
        for (int mt = 0; mt < 4; ++mt) {
            int ao = (wm + mt * 16 + lc) * 32 + lq * 8;
            ah[mt] = *(const short8*)(Ah + ao);
            al[mt] = *(const short8*)(Al + ao);
        }
#pragma unroll
        for (int nt = 0; nt < 2; ++nt) {
            int bo = (wn + nt * 16 + lc) * 32 + lq * 8;
            short8 bh = *(const short8*)(B0h + bo);
            short8 bv = *(const short8*)(B0l + bo);
#pragma unroll
            for (int mt = 0; mt < 4; ++mt) {
                MFMA(acc[mt][nt], ah[mt], bh);
                MFMA(acc[mt][nt], ah[mt], bv);
                MFMA(acc[mt][nt], al[mt], bh);
            }
        }
    }

#pragma unroll
    for (int nt = 0; nt < 2; ++nt) {
        const int col = col0 + wn + nt * 16 + lc;
#pragma unroll
        for (int mt = 0; mt < 4; ++mt) {
            const int rowb = row0 + wm + mt * 16;
#pragma unroll
            for (int r = 0; r < 4; ++r)
                u[(size_t)(rowb + lq * 4 + r) * Hn + col] = acc[mt][nt][r];
        }
    }
}

// ---------------- ga_{l-1} = (ga_l @ Wz) o mask' : NT vs WzT ----------------

__global__ __launch_bounds__(256) void bwd_g_mfma(
    const unsigned short* __restrict__ gah, const unsigned short* __restrict__ gal,
    const unsigned short* __restrict__ WzTh, const unsigned short* __restrict__ WzTl,
    const unsigned short* __restrict__ maskprev,
    unsigned short* __restrict__ goh, unsigned short* __restrict__ gol)
{
    __shared__ __align__(16) char smem[24576];
    unsigned short* Ah  = (unsigned short*)smem;
    unsigned short* Al  = (unsigned short*)(smem + 8192);
    unsigned short* B0h = (unsigned short*)(smem + 16384);
    unsigned short* B0l = (unsigned short*)(smem + 20480);

    const int tid = threadIdx.x;
    const int w = tid >> 6, lane = tid & 63;
    const int lq = lane >> 4, lc = lane & 15;
    const int wm = (w & 1) * 64, wn = (w >> 1) * 32;
    const int row0 = blockIdx.x * 128, col0 = blockIdx.y * 64;
    const int sr = lane >> 2, sk = (lane & 3) * 8;

    f32x4 acc[4][2];
#pragma unroll
    for (int i = 0; i < 4; ++i)
#pragma unroll
        for (int j = 0; j < 2; ++j)
#pragma unroll
            for (int r = 0; r < 4; ++r) acc[i][j][r] = 0.f;

    for (int k0 = 0; k0 < Hn; k0 += 32) {
        __syncthreads();
        for (int c = w; c < 8; c += 4) {
            size_t go = (size_t)(row0 + c * 16 + sr) * Hn + k0 + sk;
            gload16(gah + go, Ah + c * 512);
            gload16(gal + go, Al + c * 512);
        }
        {
            int c = w;
            size_t go = (size_t)(col0 + c * 16 + sr) * Hn + k0 + sk;
            gload16(WzTh + go, B0h + c * 512);
            gload16(WzTl + go, B0l + c * 512);
        }
        __syncthreads();
        short8 ah[4], al[4];
#pragma unroll
        for (int mt = 0; mt < 4; ++mt) {
            int ao = (wm + mt * 16 + lc) * 32 + lq * 8;
            ah[mt] = *(const short8*)(Ah + ao);
            al[mt] = *(const short8*)(Al + ao);
        }
#pragma unroll
        for (int nt = 0; nt < 2; ++nt) {
            int bo = (wn + nt * 16 + lc) * 32 + lq * 8;
            short8 bh = *(const short8*)(B0h + bo);
            short8 bv = *(const short8*)(B0l + bo);
#pragma unroll
            for (int mt = 0; mt < 4; ++mt) {
                MFMA(acc[mt][nt], ah[mt], bh);
                MFMA(acc[mt][nt], ah[mt], bv);
                MFMA(acc[mt][nt], al[mt], bh);
            }
        }
    }

#pragma unroll
    for (int nt = 0; nt < 2; ++nt) {
        const int colb = col0 + wn + nt * 16;
        const int col = colb + lc;
#pragma unroll
        for (int mt = 0; mt < 4; ++mt) {
            const int rowb = row0 + wm + mt * 16;
#pragma unroll
            for (int r = 0; r < 4; ++r) {
                int row = rowb + lq * 4 + r;
                unsigned short wbits = maskprev[(size_t)row * 32 + (colb >> 4)];
                float f = ((wbits >> lc) & 1) ? 1.f : NS;
                float v = acc[mt][nt][r] * f;
                unsigned short h, l; split2(v, h, l);
                size_t o = (size_t)row * Hn + col;
                goh[o] = h; gol[o] = l;
            }
        }
    }
}

// ---------------- gx += (2u o ga)@WqT' + ga@WlT' : 64x64 tile ----------------

__global__ __launch_bounds__(256) void bwd_x_mfma(
    const unsigned short* __restrict__ gah, const unsigned short* __restrict__ gal,
    const float* __restrict__ u,
    const unsigned short* __restrict__ WqTh, const unsigned short* __restrict__ WqTl,
    const unsigned short* __restrict__ WlTh, const unsigned short* __restrict__ WlTl,
    float* __restrict__ gx, int addTo)
{
    __shared__ __align__(16) char smem[32768];
    unsigned short* A1h = (unsigned short*)smem;            // [64][32] each
    unsigned short* A1l = (unsigned short*)(smem + 4096);
    unsigned short* A2h = (unsigned short*)(smem + 8192);
    unsigned short* A2l = (unsigned short*)(smem + 12288);
    unsigned short* Bqh = (unsigned short*)(smem + 16384);
    unsigned short* Bql = (unsigned short*)(smem + 20480);
    unsigned short* Blh = (unsigned short*)(smem + 24576);
    unsigned short* Bll = (unsigned short*)(smem + 28672);

    const int tid = threadIdx.x;
    const int w = tid >> 6, lane = tid & 63;
    const int lq = lane >> 4, lc = lane & 15;
    const int wm = (w & 1) * 32, wn = (w >> 1) * 32;
    const int row0 = blockIdx.x * 64, col0 = blockIdx.y * 64;
    const int sr = lane >> 2, sk = (lane & 3) * 8;
    const int ar = tid >> 2, as = (tid & 3) * 8;

    f32x4 acc[2][2];
#pragma unroll
    for (int i = 0; i < 2; ++i)
#pragma unroll
        for (int j = 0; j < 2; ++j)
#pragma unroll
            for (int r = 0; r < 4; ++r) acc[i][j][r] = 0.f;

    for (int k0 = 0; k0 < Hn; k0 += 32) {
        __syncthreads();
        {
            int c = w;
            size_t go = (size_t)(col0 + c * 16 + sr) * Hn + k0 + sk;
            gload16(WqTh + go, Bqh + c * 512);
            gload16(WqTl + go, Bql + c * 512);
            gload16(WlTh + go, Blh + c * 512);
            gload16(WlTl + go, Bll + c * 512);
        }
        {
            size_t gb = (size_t)(row0 + ar) * Hn + k0 + as;
            float4 u0 = *(const float4*)(u + gb);
            float4 u1 = *(const float4*)(u + gb + 4);
            ushort4 h0 = *(const ushort4*)(gah + gb);
            ushort4 h1 = *(const ushort4*)(gah + gb + 4);
            ushort4 l0 = *(const ushort4*)(gal + gb);
            ushort4 l1 = *(const ushort4*)(gal + gb + 4);
            int lo_ = ar * 32 + as;
            *(ushort4*)(A2h + lo_) = h0; *(ushort4*)(A2h + lo_ + 4) = h1;
            *(ushort4*)(A2l + lo_) = l0; *(ushort4*)(A2l + lo_ + 4) = l1;
            ushort4 oh, ol;
            float g, a1;
            g = bf2f(h0.x) + bf2f(l0.x); a1 = 2.f * u0.x * g; split2(a1, oh.x, ol.x);
            g = bf2f(h0.y) + bf2f(l0.y); a1 = 2.f * u0.y * g; split2(a1, oh.y, ol.y);
            g = bf2f(h0.z) + bf2f(l0.z); a1 = 2.f * u0.z * g; split2(a1, oh.z, ol.z);
            g = bf2f(h0.w) + bf2f(l0.w); a1 = 2.f * u0.w * g; split2(a1, oh.w, ol.w);
            *(ushort4*)(A1h + lo_) = oh; *(ushort4*)(A1l + lo_) = ol;
            g = bf2f(h1.x) + bf2f(l1.x); a1 = 2.f * u1.x * g; split2(a1, oh.x, ol.x);
            g = bf2f(h1.y) + bf2f(l1.y); a1 = 2.f * u1.y * g; split2(a1, oh.y, ol.y);
            g = bf2f(h1.z) + bf2f(l1.z); a1 = 2.f * u1.z * g; split2(a1, oh.z, ol.z);
            g = bf2f(h1.w) + bf2f(l1.w); a1 = 2.f * u1.w * g; split2(a1, oh.w, ol.w);
            *(ushort4*)(A1h + lo_ + 4) = oh; *(ushort4*)(A1l + lo_ + 4) = ol;
        }
        __syncthreads();
        short8 a1h[2], a1l[2], a2h[2], a2l[2];
#pragma unroll
        for (int mt = 0; mt < 2; ++mt) {
            int ao = (wm + mt * 16 + lc) * 32 + lq * 8;
            a1h[mt] = *(const short8*)(A1h + ao);
            a1l[mt] = *(const short8*)(A1l + ao);
            a2h[mt] = *(const short8*)(A2h + ao);
            a2l[mt] = *(const short8*)(A2l + ao);
        }
#pragma unroll
        for (int nt = 0; nt < 2; ++nt) {
            int bo = (wn + nt * 16 + lc) * 32 + lq * 8;
            short8 qh = *(const short8*)(Bqh + bo);
            short8 ql_ = *(const short8*)(Bql + bo);
            short8 lh = *(const short8*)(Blh + bo);
            short8 ll_ = *(const short8*)(Bll + bo);
#pragma unroll
            for (int mt = 0; mt < 2; ++mt) {
                MFMA(acc[mt][nt], a1h[mt], qh);
                MFMA(acc[mt][nt], a1h[mt], ql_);
                MFMA(acc[mt][nt], a1l[mt], qh);
                MFMA(acc[mt][nt], a2h[mt], lh);
                MFMA(acc[mt][nt], a2h[mt], ll_);
                MFMA(acc[mt][nt], a2l[mt], lh);
            }
        }
    }

#pragma unroll
    for (int nt = 0; nt < 2; ++nt) {
        const int col = col0 + wn + nt * 16 + lc;
#pragma unroll
        for (int mt = 0; mt < 2; ++mt) {
            const int rowb = row0 + wm + mt * 16;
#pragma unroll
            for (int r = 0; r < 4; ++r) {
                size_t o = (size_t)(rowb + lq * 4 + r) * Dn + col;
                float v = acc[mt][nt][r];
                if (addTo) v += gx[o];
                gx[o] = v;
            }
        }
    }
}

// ---------------- small kernels ----------------

__global__ __launch_bounds__(256) void ga_init(
    const float* __restrict__ wz_out, const unsigned short* __restrict__ mask9,
    unsigned short* __restrict__ gh, unsigned short* __restrict__ gl)
{
    int i = blockIdx.x * 256 + threadIdx.x;
    int e = i << 2;
    int b = e >> 9, h = e & 511;
    unsigned short wbits = mask9[(size_t)b * 32 + (h >> 4)];
    float4 wv = *(const float4*)(wz_out + h);
    int sh = h & 15;
    ushort4 oh, ol;
    float f;
    f = wv.x * (((wbits >> (sh + 0)) & 1) ? 1.f : NS); split2(f, oh.x, ol.x);
    f = wv.y * (((wbits >> (sh + 1)) & 1) ? 1.f : NS); split2(f, oh.y, ol.y);
    f = wv.z * (((wbits >> (sh + 2)) & 1) ? 1.f : NS); split2(f, oh.z, ol.z);
    f = wv.w * (((wbits >> (sh + 3)) & 1) ? 1.f : NS); split2(f, oh.w, ol.w);
    *(ushort4*)(gh + e) = oh;
    *(ushort4*)(gl + e) = ol;
}

__global__ __launch_bounds__(256) void rowdot_kernel(
    const float* __restrict__ x, const float* __restrict__ wq_out, float* __restrict__ s) {
    const int b = blockIdx.x * 4 + (threadIdx.x >> 6);
    const int lane = threadIdx.x & 63;
    float v = x[(size_t)b * Dn + lane] * wq_out[lane] +
              x[(size_t)b * Dn + 64 + lane] * wq_out[64 + lane];
#pragma unroll
    for (int off = 32; off > 0; off >>= 1) v += __shfl_down(v, off, 64);
    if (lane == 0) s[b] = v;
}

__global__ __launch_bounds__(256) void final_kernel(
    float* __restrict__ out, const float* __restrict__ x, const float* __restrict__ s,
    const float* __restrict__ wq_out, const float* __restrict__ wl_out) {
    const int i = blockIdx.x * 256 + threadIdx.x;
    const int base = i << 2;
    const int b = base >> 7;
    const int d = base & (Dn - 1);
    float4 g = *(const float4*)(out + base);
    float4 xv = *(const float4*)(x + base);
    float4 wq = *(const float4*)(wq_out + d);
    float4 wl = *(const float4*)(wl_out + d);
    const float sb = s[b];
    float4 o;
    o.x = 0.5f * g.x + sb * wq.x + 0.5f * wl.x + 0.5f * xv.x;
    o.y = 0.5f * g.y + sb * wq.y + 0.5f * wl.y + 0.5f * xv.y;
    o.z = 0.5f * g.z + sb * wq.z + 0.5f * wl.z + 0.5f * xv.z;
    o.w = 0.5f * g.w + sb * wq.w + 0.5f * wl.w + 0.5f * xv.w;
    *(float4*)(out + base) = o;
}

// ---------------- launcher ----------------

extern "C" void kernel_launch(void* const* d_in, const int* in_sizes, int n_in,
                              void* d_out, int out_size, void* d_ws, size_t ws_size,
                              hipStream_t stream) {
    (void)in_sizes; (void)n_in; (void)out_size; (void)ws_size;
    const float* x      = (const float*)d_in[0];
    const float* Wq     = (const float*)d_in[1];
    const float* Wl     = (const float*)d_in[2];
    const float* bl     = (const float*)d_in[3];
    const float* Wz     = (const float*)d_in[4];
    const float* wz_out = (const float*)d_in[5];
    const float* wq_out = (const float*)d_in[6];
    const float* wl_out = (const float*)d_in[7];
    float* out = (float*)d_out;

    char* p = (char*)d_ws;
    #define CARVE(name, bytes) unsigned short* name = (unsigned short*)p; p += (((size_t)(bytes)) + 255) & ~(size_t)255;
    CARVE(xh,  (size_t)Bn*Dn*2)  CARVE(xl,  (size_t)Bn*Dn*2)
    CARVE(Wqh, (size_t)Ln*Hn*Dn*2) CARVE(Wql, (size_t)Ln*Hn*Dn*2)
    CARVE(Wlh, (size_t)Ln*Hn*Dn*2) CARVE(Wll, (size_t)Ln*Hn*Dn*2)
    CARVE(WqTh,(size_t)Ln*Hn*Dn*2) CARVE(WqTl,(size_t)Ln*Hn*Dn*2)
    CARVE(WlTh,(size_t)Ln*Hn*Dn*2) CARVE(WlTl,(size_t)Ln*Hn*Dn*2)
    CARVE(Wzh, (size_t)(Ln-1)*Hn*Hn*2) CARVE(Wzl, (size_t)(Ln-1)*Hn*Hn*2)
    CARVE(WzTh,(size_t)(Ln-1)*Hn*Hn*2) CARVE(WzTl,(size_t)(Ln-1)*Hn*Hn*2)
    CARVE(zAh, (size_t)Bn*Hn*2) CARVE(zAl, (size_t)Bn*Hn*2)
    CARVE(zBh, (size_t)Bn*Hn*2) CARVE(zBl, (size_t)Bn*Hn*2)
    float* uBuf = (float*)p; p += (size_t)Bn*Hn*4;
    float* s    = (float*)p; p += (size_t)Bn*4;
    unsigned short* mask16 = (unsigned short*)p; p += (size_t)Ln*Bn*32*2;
    #undef CARVE

    // prep: splits + transposed splits
    split_flat<<<(Bn*Dn/4 + 255)/256, 256, 0, stream>>>(x, xh, xl, Bn*Dn/4);
    split_flat<<<(Ln*Hn*Dn/4 + 255)/256, 256, 0, stream>>>(Wq, Wqh, Wql, Ln*Hn*Dn/4);
    split_flat<<<(Ln*Hn*Dn/4 + 255)/256, 256, 0, stream>>>(Wl, Wlh, Wll, Ln*Hn*Dn/4);
    split_flat<<<((Ln-1)*Hn*Hn/4 + 255)/256, 256, 0, stream>>>(Wz, Wzh, Wzl, (Ln-1)*Hn*Hn/4);
    transpose_split<<<dim3(Hn/32, Dn/32, Ln), 256, 0, stream>>>(Wq, WqTh, WqTl, Hn, Dn);
    transpose_split<<<dim3(Hn/32, Dn/32, Ln), 256, 0, stream>>>(Wl, WlTh, WlTl, Hn, Dn);
    transpose_split<<<dim3(Hn/32, Hn/32, Ln-1), 256, 0, stream>>>(Wz, WzTh, WzTl, Hn, Hn);

    rowdot_kernel<<<Bn/4, 256, 0, stream>>>(x, wq_out, s);

    const dim3 gF(Bn/128, Hn/64);  // 64 x 8

    // forward: z_l hi/lo in (l even ? zA : zB)
    fwd_mfma<<<gF, 256, 0, stream>>>(xh, xl, nullptr, nullptr, nullptr, nullptr,
        Wqh, Wql, Wlh, Wll, bl, zAh, zAl, mask16, 0);
    for (int l = 1; l < Ln; ++l) {
        const unsigned short* zh  = (l & 1) ? zAh : zBh;
        const unsigned short* zl_ = (l & 1) ? zAl : zBl;
        unsigned short* oh  = (l & 1) ? zBh : zAh;
        unsigned short* ol_ = (l & 1) ? zBl : zAl;
        fwd_mfma<<<gF, 256, 0, stream>>>(xh, xl, zh, zl_,
            Wzh + (size_t)(l-1)*Hn*Hn, Wzl + (size_t)(l-1)*Hn*Hn,
            Wqh + (size_t)l*Hn*Dn, Wql + (size_t)l*Hn*Dn,
            Wlh + (size_t)l*Hn*Dn, Wll + (size_t)l*Hn*Dn,
            bl + (size_t)l*Hn, oh, ol_, mask16 + (size_t)l*Bn*32, 1);
    }

    // backward: ga_9 -> zA slots (z8 dead), ping-pong downward
    ga_init<<<(Bn*Hn/4)/256, 256, 0, stream>>>(wz_out, mask16 + (size_t)9*Bn*32, zAh, zAl);
    for (int l = Ln - 1; l >= 0; --l) {
        int sidx = (Ln - 1 - l) & 1;
        const unsigned short* gh_ = sidx ? zBh : zAh;
        const unsigned short* gl_ = sidx ? zBl : zAl;
        gemm_u_mfma<<<gF, 256, 0, stream>>>(xh, xl,
            Wqh + (size_t)l*Hn*Dn, Wql + (size_t)l*Hn*Dn, uBuf);
        bwd_x_mfma<<<dim3(Bn/64, Dn/64), 256, 0, stream>>>(gh_, gl_, uBuf,
            WqTh + (size_t)l*Dn*Hn, WqTl + (size_t)l*Dn*Hn,
            WlTh + (size_t)l*Dn*Hn, WlTl + (size_t)l*Dn*Hn,
            out, (l == Ln - 1) ? 0 : 1);
        if (l > 0) {
            unsigned short* oh  = sidx ? zAh : zBh;
            unsigned short* ol_ = sidx ? zAl : zBl;
            bwd_g_mfma<<<gF, 256, 0, stream>>>(gh_, gl_,
                WzTh + (size_t)(l-1)*Hn*Hn, WzTl + (size_t)(l-1)*Hn*Hn,
                mask16 + (size_t)(l-1)*Bn*32, oh, ol_);
        }
    }

    final_kernel<<<(Bn*Dn/4)/256, 256, 0, stream>>>(out, x, s, wq_out, wl_out);
}